// Round 4
// baseline (152.932 us; speedup 1.0000x reference)
//
#include <hip/hip_runtime.h>

// ConvCapsLayer: A=32,B=32,K=3,P=4,STRIDE=2,ITERS=3 — all fp32
// x: (2,32,32,512) f32   weights: (288,32,16) f32   out: (450,512) f32
// One WAVE per (patch n, out-capsule j). Lane owns i = lane + 64k, k=0..4
// (k=4 only for lane<32). v[5][16] in registers. All routing reductions are
// in-wave (DPP/swizzle split-butterfly + readlane broadcast): NO LDS, NO
// __syncthreads. Block = 256 threads = 4 waves = 4 consecutive j's sharing
// one patch n (x L1 reuse only).

#define OH 15
#define OW 15
#define NITERS 3
#define EPS_ 1e-8f

__global__ __launch_bounds__(256, 4) void convcaps_kernel(
    const float* __restrict__ x,   // (2,32,32,512)
    const float* __restrict__ w,   // (288,32,16)
    float* __restrict__ out)       // (450,512)
{
    const int blk  = blockIdx.x;      // 0..3599
    const int n    = blk >> 3;        // patch 0..449
    const int jg   = blk & 7;
    const int t    = threadIdx.x;
    const int wv   = t >> 6;          // 0..3
    const int lane = t & 63;
    const int j    = jg * 4 + wv;     // out capsule 0..31

    const int batch = n / (OH * OW);
    const int rem   = n - batch * OH * OW;
    const int oy    = rem / OW;
    const int ox    = rem - oy * OW;

    const bool has5 = (lane < 32);

    float v[5][16];
    float logit[5] = {0.f, 0.f, 0.f, 0.f, 0.f};

    // ---- compute v[k][p*4+q] = sum_r X[i,p,r] * W[i,j,r,q], i = lane+64k ----
#pragma unroll
    for (int k = 0; k < 5; ++k) {
        if (k == 4 && !has5) {
#pragma unroll
            for (int q = 0; q < 16; ++q) v[4][q] = 0.f;
        } else {
            const int i  = lane + 64 * k;
            const int a  = i & 31;
            const int kw = (i >> 5) % 3;
            const int kh = i / 96;
            const int h  = oy * 2 + kh;
            const int wc = ox * 2 + kw;

            const float4* xv = reinterpret_cast<const float4*>(
                x + (((size_t)(batch * 32 + h) * 32 + wc) * 512 + a * 16));
            float4 x0 = xv[0], x1 = xv[1], x2 = xv[2], x3 = xv[3];
            float xr[16] = { x0.x,x0.y,x0.z,x0.w, x1.x,x1.y,x1.z,x1.w,
                             x2.x,x2.y,x2.z,x2.w, x3.x,x3.y,x3.z,x3.w };

            const float4* wp = reinterpret_cast<const float4*>(
                w + ((size_t)i * 32 + j) * 16);
            float4 w0 = wp[0], w1 = wp[1], w2 = wp[2], w3 = wp[3];
            float wr[16] = { w0.x,w0.y,w0.z,w0.w, w1.x,w1.y,w1.z,w1.w,
                             w2.x,w2.y,w2.z,w2.w, w3.x,w3.y,w3.z,w3.w };

#pragma unroll
            for (int p = 0; p < 4; ++p)
#pragma unroll
                for (int q = 0; q < 4; ++q)
                    v[k][p*4+q] = fmaf(xr[p*4+0], wr[0*4+q],
                                  fmaf(xr[p*4+1], wr[1*4+q],
                                  fmaf(xr[p*4+2], wr[2*4+q],
                                       xr[p*4+3] * wr[3*4+q])));
        }
    }

#pragma unroll
    for (int it = 0; it < NITERS; ++it) {
        // ---- routing weights r[k] ----
        float r[5];
        if (it == 0) {
            const float u = 1.0f / 288.0f;
            r[0]=u; r[1]=u; r[2]=u; r[3]=u; r[4] = has5 ? u : 0.f;
        } else {
            float ml = fmaxf(fmaxf(logit[0], logit[1]), fmaxf(logit[2], logit[3]));
            ml = fmaxf(ml, has5 ? logit[4] : -1e30f);
#pragma unroll
            for (int off = 1; off < 64; off <<= 1)
                ml = fmaxf(ml, __shfl_xor(ml, off));
            float e0 = __expf(logit[0]-ml), e1 = __expf(logit[1]-ml);
            float e2 = __expf(logit[2]-ml), e3 = __expf(logit[3]-ml);
            float e4 = has5 ? __expf(logit[4]-ml) : 0.f;
            float se = e0+e1+e2+e3+e4;
#pragma unroll
            for (int off = 1; off < 64; off <<= 1)
                se += __shfl_xor(se, off);
            float rinv = 1.0f / se;
            r[0]=e0*rinv; r[1]=e1*rinv; r[2]=e2*rinv; r[3]=e3*rinv; r[4]=e4*rinv;
        }

        // ---- local weighted sum: c[q] = sum_k r[k]*v[k][q] ----
        float c[16];
#pragma unroll
        for (int q = 0; q < 16; ++q)
            c[q] = fmaf(r[0], v[0][q], fmaf(r[1], v[1][q],
                   fmaf(r[2], v[2][q], fmaf(r[3], v[3][q], r[4]*v[4][q]))));

        // ---- cross-lane sum of 16 comps over 64 lanes (split butterfly) ----
        // full steps (DPP quad_perm, cheap):
#pragma unroll
        for (int q = 0; q < 16; ++q) c[q] += __shfl_xor(c[q], 1);
#pragma unroll
        for (int q = 0; q < 16; ++q) c[q] += __shfl_xor(c[q], 2);
        // split steps: after these, quad m = (lane>>2) holds comp m (dup x4)
        float s8[8];
        {
            const bool b = (lane >> 2) & 1;
#pragma unroll
            for (int m = 0; m < 8; ++m) {
                float send = b ? c[2*m]   : c[2*m+1];
                float keep = b ? c[2*m+1] : c[2*m];
                s8[m] = keep + __shfl_xor(send, 4);
            }
        }
        float s4[4];
        {
            const bool b = (lane >> 3) & 1;
#pragma unroll
            for (int m = 0; m < 4; ++m) {
                float send = b ? s8[2*m]   : s8[2*m+1];
                float keep = b ? s8[2*m+1] : s8[2*m];
                s4[m] = keep + __shfl_xor(send, 8);
            }
        }
        float s2[2];
        {
            const bool b = (lane >> 4) & 1;
#pragma unroll
            for (int m = 0; m < 2; ++m) {
                float send = b ? s4[2*m]   : s4[2*m+1];
                float keep = b ? s4[2*m+1] : s4[2*m];
                s2[m] = keep + __shfl_xor(send, 16);
            }
        }
        float s1;
        {
            const bool b = (lane >> 5) & 1;
            float send = b ? s2[0] : s2[1];
            float keep = b ? s2[1] : s2[0];
            s1 = keep + __shfl_xor(send, 32);
        }

        // ---- squash: n2 = sum of squares over the 16 quad-held comps ----
        float t2 = s1 * s1;
        t2 += __shfl_xor(t2, 4);
        t2 += __shfl_xor(t2, 8);
        t2 += __shfl_xor(t2, 16);
        t2 += __shfl_xor(t2, 32);
        const float n2 = t2;
        const float scale = n2 / ((1.0f + n2) * sqrtf(n2 + EPS_));
        const float pval = s1 * scale;   // comp (lane>>2) of p

        if (it < NITERS - 1) {
            // broadcast p[16] to all lanes: quad-leader readlane (in-wave, no LDS)
            float p[16];
#pragma unroll
            for (int q = 0; q < 16; ++q) p[q] = __shfl(pval, q * 4);
            // logits update: logit[k] += v[k][:] . p    (v[4]=0 for !has5)
#pragma unroll
            for (int k = 0; k < 5; ++k) {
                float d = 0.f;
#pragma unroll
                for (int q = 0; q < 16; ++q) d = fmaf(v[k][q], p[q], d);
                logit[k] += d;
            }
        } else {
            if ((lane & 3) == 0)
                out[(size_t)n * 512 + j * 16 + (lane >> 2)] = pval;
        }
    }
}

extern "C" void kernel_launch(void* const* d_in, const int* in_sizes, int n_in,
                              void* d_out, int out_size, void* d_ws, size_t ws_size,
                              hipStream_t stream) {
    const float* x = (const float*)d_in[0];
    const float* w = (const float*)d_in[1];
    float* out = (float*)d_out;
    const int nblocks = 450 * 8;   // (n) x (j-groups of 4 waves)
    convcaps_kernel<<<nblocks, 256, 0, stream>>>(x, w, out);
}

// Round 5
// 114.683 us; speedup vs baseline: 1.3335x; 1.3335x over previous
//
#include <hip/hip_runtime.h>

// ConvCapsLayer: A=32,B=32,K=3,P=4,STRIDE=2,ITERS=3 — all fp32
// x: (2,32,32,512) f32   weights: (288,32,16) f32   out: (450,512) f32
// One WAVE per (patch n, out-capsule j). Lane owns i = lane + 64k, k=0..4
// (k=4 only for lane<32). v[5][16] in registers. All routing reductions are
// in-wave (split-butterfly + readlane broadcast): NO LDS, NO __syncthreads.
// Block = 256 threads = 4 independent waves = 4 consecutive j's sharing one
// patch n (x L1 reuse only).
// NOTE: __launch_bounds__ min-waves MUST stay <=3: live set ~84 VGPR; forcing
// 4 waves/EU caps at 64 VGPR -> 170MB of scratch spill traffic (measured R4).

#define OH 15
#define OW 15
#define NITERS 3
#define EPS_ 1e-8f

__global__ __launch_bounds__(256, 3) void convcaps_kernel(
    const float* __restrict__ x,   // (2,32,32,512)
    const float* __restrict__ w,   // (288,32,16)
    float* __restrict__ out)       // (450,512)
{
    const int blk  = blockIdx.x;      // 0..3599
    const int n    = blk >> 3;        // patch 0..449
    const int jg   = blk & 7;
    const int t    = threadIdx.x;
    const int wv   = t >> 6;          // 0..3
    const int lane = t & 63;
    const int j    = jg * 4 + wv;     // out capsule 0..31

    const int batch = n / (OH * OW);
    const int rem   = n - batch * OH * OW;
    const int oy    = rem / OW;
    const int ox    = rem - oy * OW;

    const bool has5 = (lane < 32);

    float v[5][16];
    float logit[5] = {0.f, 0.f, 0.f, 0.f, 0.f};

    // ---- compute v[k][p*4+q] = sum_r X[i,p,r] * W[i,j,r,q], i = lane+64k ----
#pragma unroll
    for (int k = 0; k < 5; ++k) {
        if (k == 4 && !has5) {
#pragma unroll
            for (int q = 0; q < 16; ++q) v[4][q] = 0.f;
        } else {
            const int i  = lane + 64 * k;
            const int a  = i & 31;
            const int kw = (i >> 5) % 3;
            const int kh = i / 96;
            const int h  = oy * 2 + kh;
            const int wc = ox * 2 + kw;

            const float4* xv = reinterpret_cast<const float4*>(
                x + (((size_t)(batch * 32 + h) * 32 + wc) * 512 + a * 16));
            float4 x0 = xv[0], x1 = xv[1], x2 = xv[2], x3 = xv[3];
            float xr[16] = { x0.x,x0.y,x0.z,x0.w, x1.x,x1.y,x1.z,x1.w,
                             x2.x,x2.y,x2.z,x2.w, x3.x,x3.y,x3.z,x3.w };

            const float4* wp = reinterpret_cast<const float4*>(
                w + ((size_t)i * 32 + j) * 16);
            float4 w0 = wp[0], w1 = wp[1], w2 = wp[2], w3 = wp[3];
            float wr[16] = { w0.x,w0.y,w0.z,w0.w, w1.x,w1.y,w1.z,w1.w,
                             w2.x,w2.y,w2.z,w2.w, w3.x,w3.y,w3.z,w3.w };

#pragma unroll
            for (int p = 0; p < 4; ++p)
#pragma unroll
                for (int q = 0; q < 4; ++q)
                    v[k][p*4+q] = fmaf(xr[p*4+0], wr[0*4+q],
                                  fmaf(xr[p*4+1], wr[1*4+q],
                                  fmaf(xr[p*4+2], wr[2*4+q],
                                       xr[p*4+3] * wr[3*4+q])));
        }
    }

#pragma unroll
    for (int it = 0; it < NITERS; ++it) {
        // ---- routing weights r[k] ----
        float r[5];
        if (it == 0) {
            const float u = 1.0f / 288.0f;
            r[0]=u; r[1]=u; r[2]=u; r[3]=u; r[4] = has5 ? u : 0.f;
        } else {
            float ml = fmaxf(fmaxf(logit[0], logit[1]), fmaxf(logit[2], logit[3]));
            ml = fmaxf(ml, has5 ? logit[4] : -1e30f);
#pragma unroll
            for (int off = 1; off < 64; off <<= 1)
                ml = fmaxf(ml, __shfl_xor(ml, off));
            float e0 = __expf(logit[0]-ml), e1 = __expf(logit[1]-ml);
            float e2 = __expf(logit[2]-ml), e3 = __expf(logit[3]-ml);
            float e4 = has5 ? __expf(logit[4]-ml) : 0.f;
            float se = e0+e1+e2+e3+e4;
#pragma unroll
            for (int off = 1; off < 64; off <<= 1)
                se += __shfl_xor(se, off);
            float rinv = 1.0f / se;
            r[0]=e0*rinv; r[1]=e1*rinv; r[2]=e2*rinv; r[3]=e3*rinv; r[4]=e4*rinv;
        }

        // ---- local weighted sum: c[q] = sum_k r[k]*v[k][q] ----
        float c[16];
#pragma unroll
        for (int q = 0; q < 16; ++q)
            c[q] = fmaf(r[0], v[0][q], fmaf(r[1], v[1][q],
                   fmaf(r[2], v[2][q], fmaf(r[3], v[3][q], r[4]*v[4][q]))));

        // ---- cross-lane sum of 16 comps over 64 lanes (split butterfly) ----
#pragma unroll
        for (int q = 0; q < 16; ++q) c[q] += __shfl_xor(c[q], 1);
#pragma unroll
        for (int q = 0; q < 16; ++q) c[q] += __shfl_xor(c[q], 2);
        // split steps: after these, quad m = (lane>>2) holds comp m (dup x4)
        float s8[8];
        {
            const bool b = (lane >> 2) & 1;
#pragma unroll
            for (int m = 0; m < 8; ++m) {
                float send = b ? c[2*m]   : c[2*m+1];
                float keep = b ? c[2*m+1] : c[2*m];
                s8[m] = keep + __shfl_xor(send, 4);
            }
        }
        float s4[4];
        {
            const bool b = (lane >> 3) & 1;
#pragma unroll
            for (int m = 0; m < 4; ++m) {
                float send = b ? s8[2*m]   : s8[2*m+1];
                float keep = b ? s8[2*m+1] : s8[2*m];
                s4[m] = keep + __shfl_xor(send, 8);
            }
        }
        float s2[2];
        {
            const bool b = (lane >> 4) & 1;
#pragma unroll
            for (int m = 0; m < 2; ++m) {
                float send = b ? s4[2*m]   : s4[2*m+1];
                float keep = b ? s4[2*m+1] : s4[2*m];
                s2[m] = keep + __shfl_xor(send, 16);
            }
        }
        float s1;
        {
            const bool b = (lane >> 5) & 1;
            float send = b ? s2[0] : s2[1];
            float keep = b ? s2[1] : s2[0];
            s1 = keep + __shfl_xor(send, 32);
        }

        // ---- squash: n2 = sum of squares over the 16 quad-held comps ----
        float t2 = s1 * s1;
        t2 += __shfl_xor(t2, 4);
        t2 += __shfl_xor(t2, 8);
        t2 += __shfl_xor(t2, 16);
        t2 += __shfl_xor(t2, 32);
        const float n2 = t2;
        const float scale = n2 / ((1.0f + n2) * sqrtf(n2 + EPS_));
        const float pval = s1 * scale;   // comp (lane>>2) of p

        if (it < NITERS - 1) {
            // broadcast p[16] to all lanes: quad-leader readlane (in-wave, no LDS)
            float p[16];
#pragma unroll
            for (int q = 0; q < 16; ++q) p[q] = __shfl(pval, q * 4);
            // logits update: logit[k] += v[k][:] . p    (v[4]=0 for !has5)
#pragma unroll
            for (int k = 0; k < 5; ++k) {
                float d = 0.f;
#pragma unroll
                for (int q = 0; q < 16; ++q) d = fmaf(v[k][q], p[q], d);
                logit[k] += d;
            }
        } else {
            if ((lane & 3) == 0)
                out[(size_t)n * 512 + j * 16 + (lane >> 2)] = pval;
        }
    }
}

extern "C" void kernel_launch(void* const* d_in, const int* in_sizes, int n_in,
                              void* d_out, int out_size, void* d_ws, size_t ws_size,
                              hipStream_t stream) {
    const float* x = (const float*)d_in[0];
    const float* w = (const float*)d_in[1];
    float* out = (float*)d_out;
    const int nblocks = 450 * 8;   // (n) x (j-groups of 4 waves)
    convcaps_kernel<<<nblocks, 256, 0, stream>>>(x, w, out);
}

// Round 6
// 105.807 us; speedup vs baseline: 1.4454x; 1.0839x over previous
//
#include <hip/hip_runtime.h>

// ConvCapsLayer: A=32,B=32,K=3,P=4,STRIDE=2,ITERS=3 — all fp32
// x: (2,32,32,512) f32   weights: (288,32,16) f32   out: (450,512) f32
// One WAVE per (patch n, out-capsule j). Lane owns i = lane + 64k, k=0..4
// (k=4 only for lane<32). v[5][16] held packed (v2f[5][8]).
// Routing: unnormalized-softmax weighted sums (SE rides along the butterfly),
// split-FIRST butterfly (xor 1,2,4,8 split comps, 16/32 full) -> comp = lane&15.
// No LDS, no __syncthreads. Packed fp32 (v_pk_fma_f32) for all dot products.
// NOTE: __launch_bounds__ min-waves MUST stay <=3: forcing 4 waves/EU caps at
// 64 VGPR -> 170MB scratch spill traffic (measured R4).

#define OH 15
#define OW 15
#define NITERS 3
#define EPS_ 1e-8f

typedef float v2f __attribute__((ext_vector_type(2)));

__device__ __forceinline__ v2f pfma(float a, v2f b, v2f c) {
    return __builtin_elementwise_fma((v2f){a, a}, b, c);
}

__global__ __launch_bounds__(256, 3) void convcaps_kernel(
    const float* __restrict__ x,   // (2,32,32,512)
    const float* __restrict__ w,   // (288,32,16)
    float* __restrict__ out)       // (450,512)
{
    const int blk  = blockIdx.x;      // 0..3599
    const int n    = blk >> 3;        // patch 0..449
    const int jg   = blk & 7;
    const int t    = threadIdx.x;
    const int wv   = t >> 6;          // 0..3
    const int lane = t & 63;
    const int j    = jg * 4 + wv;     // out capsule 0..31

    const int batch = n / (OH * OW);
    const int rem   = n - batch * OH * OW;
    const int oy    = rem / OW;
    const int ox    = rem - oy * OW;

    const bool has5 = (lane < 32);

    v2f v[5][8];                      // v[k][p*2+qq], comps (2*qq, 2*qq+1)
    float logit[5] = {0.f, 0.f, 0.f, 0.f, 0.f};

    // ---- v[k] = X_i(4x4) * W_ij(4x4), i = lane + 64k ----
#pragma unroll
    for (int k = 0; k < 5; ++k) {
        if (k == 4 && !has5) {
#pragma unroll
            for (int m = 0; m < 8; ++m) v[4][m] = (v2f){0.f, 0.f};
        } else {
            const int i  = lane + 64 * k;
            const int a  = i & 31;
            const int kw = (i >> 5) % 3;
            const int kh = i / 96;
            const int h  = oy * 2 + kh;
            const int wc = ox * 2 + kw;

            const float4* xv = reinterpret_cast<const float4*>(
                x + (((size_t)(batch * 32 + h) * 32 + wc) * 512 + a * 16));
            float4 x0 = xv[0], x1 = xv[1], x2 = xv[2], x3 = xv[3];
            float xr[16] = { x0.x,x0.y,x0.z,x0.w, x1.x,x1.y,x1.z,x1.w,
                             x2.x,x2.y,x2.z,x2.w, x3.x,x3.y,x3.z,x3.w };

            const float4* wp = reinterpret_cast<const float4*>(
                w + ((size_t)i * 32 + j) * 16);
            float4 w0 = wp[0], w1 = wp[1], w2 = wp[2], w3 = wp[3];
            v2f wr2[4][2] = { {{w0.x,w0.y},{w0.z,w0.w}},
                              {{w1.x,w1.y},{w1.z,w1.w}},
                              {{w2.x,w2.y},{w2.z,w2.w}},
                              {{w3.x,w3.y},{w3.z,w3.w}} };

#pragma unroll
            for (int p = 0; p < 4; ++p) {
#pragma unroll
                for (int qq = 0; qq < 2; ++qq) {
                    v2f acc = (v2f){0.f, 0.f};
                    acc = pfma(xr[p*4+0], wr2[0][qq], acc);
                    acc = pfma(xr[p*4+1], wr2[1][qq], acc);
                    acc = pfma(xr[p*4+2], wr2[2][qq], acc);
                    acc = pfma(xr[p*4+3], wr2[3][qq], acc);
                    v[k][p*2+qq] = acc;
                }
            }
        }
    }

#pragma unroll
    for (int it = 0; it < NITERS; ++it) {
        // ---- unnormalized weighted sum c2 and (for it>0) SE = sum_i e_i ----
        v2f c2[8];
        float se_loc;
        if (it == 0) {
#pragma unroll
            for (int m = 0; m < 8; ++m)
                c2[m] = v[0][m] + v[1][m] + v[2][m] + v[3][m] + v[4][m];
            se_loc = 0.f;  // unused; normalizer is 288
        } else {
            const float e0 = __expf(logit[0]), e1 = __expf(logit[1]);
            const float e2 = __expf(logit[2]), e3 = __expf(logit[3]);
            const float e4 = __expf(logit[4]);
#pragma unroll
            for (int m = 0; m < 8; ++m)
                c2[m] = pfma(e0, v[0][m],
                        pfma(e1, v[1][m],
                        pfma(e2, v[2][m],
                        pfma(e3, v[3][m],
                        pfma(e4, v[4][m], (v2f){0.f, 0.f})))));
            se_loc = e0 + e1 + e2 + e3 + (has5 ? e4 : 0.f);
        }

        float c[16];
#pragma unroll
        for (int m = 0; m < 8; ++m) { c[2*m] = c2[m].x; c[2*m+1] = c2[m].y; }

        // ---- split-first butterfly: comp bit b goes to lane bit b ----
        float seR = se_loc;
        float s8[8];
        {
            const bool b = lane & 1;
#pragma unroll
            for (int m = 0; m < 8; ++m) {
                float send = b ? c[2*m]   : c[2*m+1];
                float keep = b ? c[2*m+1] : c[2*m];
                s8[m] = keep + __shfl_xor(send, 1);
            }
            seR += __shfl_xor(seR, 1);
        }
        float s4[4];
        {
            const bool b = (lane >> 1) & 1;
#pragma unroll
            for (int m = 0; m < 4; ++m) {
                float send = b ? s8[2*m]   : s8[2*m+1];
                float keep = b ? s8[2*m+1] : s8[2*m];
                s4[m] = keep + __shfl_xor(send, 2);
            }
            seR += __shfl_xor(seR, 2);
        }
        float s2v[2];
        {
            const bool b = (lane >> 2) & 1;
#pragma unroll
            for (int m = 0; m < 2; ++m) {
                float send = b ? s4[2*m]   : s4[2*m+1];
                float keep = b ? s4[2*m+1] : s4[2*m];
                s2v[m] = keep + __shfl_xor(send, 4);
            }
            seR += __shfl_xor(seR, 4);
        }
        float s1;
        {
            const bool b = (lane >> 3) & 1;
            float send = b ? s2v[0] : s2v[1];
            float keep = b ? s2v[1] : s2v[0];
            s1 = keep + __shfl_xor(send, 8);
            seR += __shfl_xor(seR, 8);
        }
        s1 += __shfl_xor(s1, 16);  seR += __shfl_xor(seR, 16);
        s1 += __shfl_xor(s1, 32);  seR += __shfl_xor(seR, 32);
        // now: s1 = sum_i (e_i or 1) * v_i[comp], comp = lane&15 (dup x4)
        //      seR = SE (all lanes)

        const float s = (it == 0) ? s1 * (1.0f / 288.0f) : s1 / seR;

        // ---- squash ----
        float t2 = s * s;
        t2 += __shfl_xor(t2, 1);
        t2 += __shfl_xor(t2, 2);
        t2 += __shfl_xor(t2, 4);
        t2 += __shfl_xor(t2, 8);
        const float n2 = t2;
        const float scale = n2 / ((1.0f + n2) * sqrtf(n2 + EPS_));
        const float pval = s * scale;   // comp (lane&15) of p

        if (it < NITERS - 1) {
            // broadcast p[16] (readlane; comp q lives at lane q)
            float p[16];
#pragma unroll
            for (int q = 0; q < 16; ++q) p[q] = __shfl(pval, q);
            v2f p2[8];
#pragma unroll
            for (int m = 0; m < 8; ++m) p2[m] = (v2f){p[2*m], p[2*m+1]};
            // logit[k] += v[k] . p
#pragma unroll
            for (int k = 0; k < 5; ++k) {
                v2f acc = (v2f){0.f, 0.f};
#pragma unroll
                for (int m = 0; m < 8; ++m)
                    acc = __builtin_elementwise_fma(v[k][m], p2[m], acc);
                logit[k] += acc.x + acc.y;
            }
        } else {
            if (lane < 16)
                out[(size_t)n * 512 + j * 16 + lane] = pval;
        }
    }
}

extern "C" void kernel_launch(void* const* d_in, const int* in_sizes, int n_in,
                              void* d_out, int out_size, void* d_ws, size_t ws_size,
                              hipStream_t stream) {
    const float* x = (const float*)d_in[0];
    const float* w = (const float*)d_in[1];
    float* out = (float*)d_out;
    const int nblocks = 450 * 8;   // (n) x (j-groups of 4 waves)
    convcaps_kernel<<<nblocks, 256, 0, stream>>>(x, w, out);
}